// Round 4
// baseline (632.644 us; speedup 1.0000x reference)
//
#include <hip/hip_runtime.h>
#include <math.h>

// CRF forward partition scan. B=512, S=1024, T=48.
// One 64-lane wave per batch element. Lane j owns tag j (lanes 48..63 clamp).
//
// R2/R3 post-mortem: float Tc[48]/Ec[48] stayed alloca->scratch even with
// template unrolling (VGPR_Count=80 both rounds; ~96 scratch reloads/step).
// R4 fix: NO aggregates at all. 96 named scalars (T0..T47, E0..E47) and
// named float4 broadcasts, macro-generated. Nothing for SROA to miss.
// __launch_bounds__(64,1) -> 512-VGPR budget, so RA won't spill either.

constexpr int kB = 512;
constexpr int kS = 1024;
constexpr int kT = 48;

#define REP12(X) X(0) X(1) X(2) X(3) X(4) X(5) X(6) X(7) X(8) X(9) X(10) X(11)

// X(i, i/4, component, i%8)
#define REP48(X) \
  X(0,0,x,0)   X(1,0,y,1)   X(2,0,z,2)   X(3,0,w,3)   \
  X(4,1,x,4)   X(5,1,y,5)   X(6,1,z,6)   X(7,1,w,7)   \
  X(8,2,x,0)   X(9,2,y,1)   X(10,2,z,2)  X(11,2,w,3)  \
  X(12,3,x,4)  X(13,3,y,5)  X(14,3,z,6)  X(15,3,w,7)  \
  X(16,4,x,0)  X(17,4,y,1)  X(18,4,z,2)  X(19,4,w,3)  \
  X(20,5,x,4)  X(21,5,y,5)  X(22,5,z,6)  X(23,5,w,7)  \
  X(24,6,x,0)  X(25,6,y,1)  X(26,6,z,2)  X(27,6,w,3)  \
  X(28,7,x,4)  X(29,7,y,5)  X(30,7,z,6)  X(31,7,w,7)  \
  X(32,8,x,0)  X(33,8,y,1)  X(34,8,z,2)  X(35,8,w,3)  \
  X(36,9,x,4)  X(37,9,y,5)  X(38,9,z,6)  X(39,9,w,7)  \
  X(40,10,x,0) X(41,10,y,1) X(42,10,z,2) X(43,10,w,3) \
  X(44,11,x,4) X(45,11,y,5) X(46,11,z,6) X(47,11,w,7)

#define DECL_TE(i,q,c,a) float T##i, E##i;
#define LOAD_TE(i,q,c,a) T##i = trans[(i)*kT + j]; E##i = __expf(T##i);
#define LOADP(q) const float4 P##q = p4[q];
#define LOADQ(q) const float4 Q##q = q4[q];
#define PASS1(i,q,c,a) am##a = fmaxf(am##a, T##i + (P##q).c);
#define PASS2(i,q,c,a) as##a = fmaf(E##i, (Q##q).c, as##a);

__global__ __launch_bounds__(64, 1) void crf_fwd(
    const float* __restrict__ feats,   // [B, S, T] fp32
    const int*   __restrict__ mask,    // [B, S] int32 (bool)
    const float* __restrict__ trans,   // [T, T] fp32
    float*       __restrict__ out)     // [1 + B]; we write out[1+b]
{
    const int b    = blockIdx.x;
    const int lane = threadIdx.x;
    const int j    = (lane < kT) ? lane : (kT - 1);  // clamp idle lanes

    __shared__ alignas(16) float p_sh[64];   // part_i
    __shared__ alignas(16) float ea_sh[64];  // exp(part_i - e_i - M_i)
    const float4* p4 = (const float4*)p_sh;
    const float4* q4 = (const float4*)ea_sh;

    // Column j of transition and its exp: 96 named scalars -> VGPRs.
    REP48(DECL_TE)
    REP48(LOAD_TE)

    const float* fb = feats + (size_t)b * kS * kT + j;  // lane-offset base
    const int*   mb = mask  + (size_t)b * kS;

    // part0 = emit[0] + transition[T-2, :]   (kT-2 == 46)
    float part = fb[0] + T46;
    p_sh[lane] = part;
    __syncthreads();

    // Depth-4 register-rotated prefetch of (emission, mask).
    float e0 = fb[(size_t)1 * kT], e1 = fb[(size_t)2 * kT],
          e2 = fb[(size_t)3 * kT], e3 = fb[(size_t)4 * kT];
    int   m0 = mb[1], m1 = mb[2], m2 = mb[3], m3 = mb[4];

    for (int t = 1; t < kS; ++t) {
        const float e  = e0;
        const int   mk = m0;
        e0 = e1; e1 = e2; e2 = e3;
        m0 = m1; m1 = m2; m2 = m3;
        const int tn = (t + 4 < kS) ? (t + 4) : (kS - 1);
        e3 = fb[(size_t)tn * kT];
        m3 = mb[tn];

        if (mk) {  // wave-uniform branch: skip masked-out steps entirely
            const float pe = part - e;  // off the M-dependent critical path

            // pass 1: M_j = max_i (T[i,j] + part_i), broadcast b128 reads.
            REP12(LOADP)
            float am0 = -INFINITY, am1 = -INFINITY, am2 = -INFINITY, am3 = -INFINITY;
            float am4 = -INFINITY, am5 = -INFINITY, am6 = -INFINITY, am7 = -INFINITY;
            REP48(PASS1)
            const float M = fmaxf(fmaxf(fmaxf(am0, am4), fmaxf(am1, am5)),
                                  fmaxf(fmaxf(am2, am6), fmaxf(am3, am7)));

            // lane i publishes exp(part_i - e_i - M_i)
            const float ea = __expf(pe - M);
            ea_sh[lane] = ea;
            __syncthreads();  // B1: ea visible; pass-1 reads of p_sh done

            // pass 2: S_j = sum_i exp(T[i,j]) * ea_i  (FMA dot product)
            REP12(LOADQ)
            float as0 = 0.f, as1 = 0.f, as2 = 0.f, as3 = 0.f;
            float as4 = 0.f, as5 = 0.f, as6 = 0.f, as7 = 0.f;
            REP48(PASS2)
            const float Ssum = ((as0 + as4) + (as1 + as5)) +
                               ((as2 + as6) + (as3 + as7));

            // val_j = 2*e_j + M_j + log(S_j); mask true so part <- val
            part = 2.0f * e + M + __logf(Ssum);
            p_sh[lane] = part;
            __syncthreads();  // B2: part visible for next step's pass 1
        }
    }

    // Final transition-only step; only end_value[:, T-1] is stored.
    {
        REP12(LOADP)
        float am0 = -INFINITY, am1 = -INFINITY, am2 = -INFINITY, am3 = -INFINITY;
        float am4 = -INFINITY, am5 = -INFINITY, am6 = -INFINITY, am7 = -INFINITY;
        REP48(PASS1)
        const float M = fmaxf(fmaxf(fmaxf(am0, am4), fmaxf(am1, am5)),
                              fmaxf(fmaxf(am2, am6), fmaxf(am3, am7)));
        const float ea = __expf(part - M);   // no emission term in final step
        ea_sh[lane] = ea;
        __syncthreads();

        REP12(LOADQ)
        float as0 = 0.f, as1 = 0.f, as2 = 0.f, as3 = 0.f;
        float as4 = 0.f, as5 = 0.f, as6 = 0.f, as7 = 0.f;
        REP48(PASS2)
        const float Ssum = ((as0 + as4) + (as1 + as5)) +
                           ((as2 + as6) + (as3 + as7));
        const float val = M + __logf(Ssum);
        if (lane == kT - 1) out[1 + b] = val;  // score[b] = end_value[b, -1]
    }
}

// out[0] = sum(score). Single wave; no barriers needed.
__global__ __launch_bounds__(64) void sum_scores(
    const float* __restrict__ sc, float* __restrict__ out)
{
    float s = 0.f;
    for (int i = (int)threadIdx.x; i < kB; i += 64) s += sc[i];
#pragma unroll
    for (int off = 32; off > 0; off >>= 1) s += __shfl_down(s, off);
    if (threadIdx.x == 0) out[0] = s;
}

extern "C" void kernel_launch(void* const* d_in, const int* in_sizes, int n_in,
                              void* d_out, int out_size, void* d_ws, size_t ws_size,
                              hipStream_t stream) {
    const float* feats = (const float*)d_in[0];
    const int*   mask  = (const int*)d_in[1];
    const float* trans = (const float*)d_in[2];
    float*       out   = (float*)d_out;

    crf_fwd<<<dim3(kB), dim3(64), 0, stream>>>(feats, mask, trans, out);
    sum_scores<<<dim3(1), dim3(64), 0, stream>>>(out + 1, out);
}